// Round 1
// 210.841 us; speedup vs baseline: 1.0599x; 1.0599x over previous
//
#include <hip/hip_runtime.h>
#include <math.h>

#define B_ 2
#define S_ 2048
#define E_ 768
#define H_ 12
#define D_ 64
#define M_ (B_*S_)   // 4096 rows total

typedef unsigned short ush;
using short8 = __attribute__((ext_vector_type(8))) short;   // 8 bf16 (4 VGPRs)
using f32x4  = __attribute__((ext_vector_type(4))) float;   // MFMA C/D

__device__ __forceinline__ ush f2b(float x) {               // fp32 -> bf16 RNE
    union { float f; unsigned u; } v; v.f = x;
    unsigned r = v.u + 0x7fffu + ((v.u >> 16) & 1u);
    return (ush)(r >> 16);
}
// fp32 pair -> packed bf16: round-half-up + v_perm_b32 (3 VALU ops).
__device__ __forceinline__ unsigned pack2(float x, float y) {
    unsigned bx = __float_as_uint(x) + 0x8000u;
    unsigned by = __float_as_uint(y) + 0x8000u;
    return __builtin_amdgcn_perm(by, bx, 0x07060302u);  // [bx.hi16 | by.hi16<<16]
}

// async global->LDS, 16B/lane. LDS dest = wave-uniform base + lane*16 (linear).
// Swizzled LDS content is achieved by permuting the per-lane GLOBAL source
// (rule 21: linear dest + inverse-swz source + swz read; XOR is an involution).
#define GLOAD16(gp, lp) __builtin_amdgcn_global_load_lds( \
    (const __attribute__((address_space(1))) void*)(gp),   \
    (__attribute__((address_space(3))) void*)(lp), 16, 0, 0)

// ---------------------------------------------------------------------------
// Kernel 0: one-time fp32->bf16 convert (q,k,v inputs + 4 weight matrices)
// and RoPE cos/sin table [S][32] float2. ~71 MB traffic, memory-bound.
// Segments by flat blockIdx.x: [0,4608) inputs, [4608,5760) weights,
// [5760,6016) rope table. All segment sizes exact (8 elems/thread).
// ---------------------------------------------------------------------------
__global__ __launch_bounds__(256) void convert_kernel(
    const float* __restrict__ q, const float* __restrict__ k, const float* __restrict__ v,
    const float* __restrict__ wq, const float* __restrict__ wk,
    const float* __restrict__ wv, const float* __restrict__ fw,
    ush* __restrict__ Xq, ush* __restrict__ Xk, ush* __restrict__ Xv,
    ush* __restrict__ Wqb, ush* __restrict__ Wkb, ush* __restrict__ Wvb,
    ush* __restrict__ Wfb, float2* __restrict__ rope)
{
    const int bid = blockIdx.x;
    const int t   = threadIdx.x;
    if (bid < 4608) {                         // 3 inputs, 1536 blocks each
        const int tz = bid / 1536, off = bid % 1536;
        const float* __restrict__ src = (tz == 0) ? q : (tz == 1) ? k : v;
        ush* __restrict__ dst = (tz == 0) ? Xq : (tz == 1) ? Xk : Xv;
        const size_t base = ((size_t)off * 256 + t) * 8;
        const float4 a = *(const float4*)&src[base];
        const float4 b = *(const float4*)&src[base + 4];
        uint4 o;
        o.x = pack2(a.x, a.y); o.y = pack2(a.z, a.w);
        o.z = pack2(b.x, b.y); o.w = pack2(b.z, b.w);
        *(uint4*)&dst[base] = o;
    } else if (bid < 5760) {                  // 4 weights, 288 blocks each
        const int id = bid - 4608;
        const int tz = id / 288, off = id % 288;
        const float* __restrict__ src = (tz == 0) ? wq : (tz == 1) ? wk : (tz == 2) ? wv : fw;
        ush* __restrict__ dst = (tz == 0) ? Wqb : (tz == 1) ? Wkb : (tz == 2) ? Wvb : Wfb;
        const size_t base = ((size_t)off * 256 + t) * 8;
        const float4 a = *(const float4*)&src[base];
        const float4 b = *(const float4*)&src[base + 4];
        uint4 o;
        o.x = pack2(a.x, a.y); o.y = pack2(a.z, a.w);
        o.z = pack2(b.x, b.y); o.w = pack2(b.z, b.w);
        *(uint4*)&dst[base] = o;
    } else {                                  // rope table: 65536 entries
        const int idx = (bid - 5760) * 256 + t;
        const int s = idx >> 5, dp = idx & 31;
        const float invf = expf(-(float)dp * (9.210340371976184f / 32.f)); // 10000^(-dp/32)
        float sn, cs;
        sincosf((float)s * invf, &sn, &cs);
        rope[idx] = make_float2(cs, sn);
    }
}

// ---------------------------------------------------------------------------
// Kernel 1: QKV projection, pure-bf16 MFMA GEMM, global_load_lds staging.
// Tile 128x64 (BN=64 == one head), BK=64, 4 waves as 2x2, wave tile 64x32,
// acc[4][2]. LDS 24 KB -> up to 6 blocks/CU; grid (32,12,3)=1152 (4.5/CU).
// LDS content is chunk-XOR-swizzled (16B chunk p of row r holds logical
// chunk p^(r&7)) so fragment ds_read_b128 is <=2-way (free, m136).
// Epilogue: RoPE via precomputed table (no sincosf), bf16 stores.
// ---------------------------------------------------------------------------
__global__ __launch_bounds__(256) void qkv_mfma_kernel(
    const ush* __restrict__ Xq, const ush* __restrict__ Xk, const ush* __restrict__ Xv,
    const ush* __restrict__ Wq, const ush* __restrict__ Wk, const ush* __restrict__ Wv,
    const float* __restrict__ bq, const float* __restrict__ bk, const float* __restrict__ bv,
    const float2* __restrict__ rope,
    ush* __restrict__ Qb, ush* __restrict__ Kb, ush* __restrict__ Vtb)
{
    const int z = blockIdx.z;
    const ush* __restrict__ X = (z == 0) ? Xq : (z == 1) ? Xk : Xv;
    const ush* __restrict__ W = (z == 0) ? Wq : (z == 1) ? Wk : Wv;
    const float* __restrict__ bias = (z == 0) ? bq : (z == 1) ? bk : bv;

    __shared__ ush As[128 * 64];   // [m][k], linear pitch 64, chunk-swizzled
    __shared__ ush Bs[64 * 64];    // [n][k]

    const int m0 = blockIdx.x * 128;
    const int h  = blockIdx.y;                 // BN == D: block owns one head
    const int n0 = h * 64;
    const int t  = threadIdx.x;
    const int wid  = t >> 6;
    const int lane = t & 63;
    const int quad = lane >> 4;
    const int l16  = lane & 15;
    const int wr = (wid >> 1) * 64;            // wave row offset (0/64)
    const int wc = (wid & 1) * 32;             // wave col offset (0/32)
    const int srow = lane >> 3;                // staging: row within 8-row group
    const int schk = lane & 7;                 // staging: physical 16B chunk

    f32x4 acc[4][2];
    #pragma unroll
    for (int i = 0; i < 4; ++i)
        #pragma unroll
        for (int j = 0; j < 2; ++j) acc[i][j] = (f32x4){0.f, 0.f, 0.f, 0.f};

    for (int kt = 0; kt < E_ / 64; ++kt) {
        const int kb = kt * 64;
        // A: wave w stages rows [w*32, w*32+32), 4 calls x 8 rows x 128B
        #pragma unroll
        for (int j = 0; j < 4; ++j) {
            const int r = wid * 32 + j * 8 + srow;
            const int c = schk ^ (r & 7);      // inverse-swizzled global chunk
            GLOAD16(&X[(size_t)(m0 + r) * E_ + kb + c * 8],
                    &As[(wid * 32 + j * 8) * 64]);
        }
        // B: wave w stages rows [w*16, w*16+16), 2 calls
        #pragma unroll
        for (int j = 0; j < 2; ++j) {
            const int r = wid * 16 + j * 8 + srow;
            const int c = schk ^ (r & 7);
            GLOAD16(&W[(size_t)(n0 + r) * E_ + kb + c * 8],
                    &Bs[(wid * 16 + j * 8) * 64]);
        }
        __syncthreads();   // drains vmcnt (compiler) -> tile visible

        #pragma unroll
        for (int ks = 0; ks < 2; ++ks) {
            short8 bfr[2];
            #pragma unroll
            for (int nj = 0; nj < 2; ++nj) {
                const int rn = wc + nj * 16 + l16;
                bfr[nj] = *(const short8*)&Bs[rn * 64 + ((quad + ks * 4) ^ (rn & 7)) * 8];
            }
            #pragma unroll
            for (int mi = 0; mi < 4; ++mi) {
                const int rm = wr + mi * 16 + l16;
                short8 a = *(const short8*)&As[rm * 64 + ((quad + ks * 4) ^ (rm & 7)) * 8];
                acc[mi][0] = __builtin_amdgcn_mfma_f32_16x16x32_bf16(a, bfr[0], acc[mi][0], 0, 0, 0);
                acc[mi][1] = __builtin_amdgcn_mfma_f32_16x16x32_bf16(a, bfr[1], acc[mi][1], 0, 0, 0);
            }
        }
        __syncthreads();   // all reads done before next tile overwrite
    }

    // ---- epilogue ----
    if (z < 2) {
        ush* __restrict__ Ob = (z == 0) ? Qb : Kb;
        #pragma unroll
        for (int nj = 0; nj < 2; ++nj) {
            const int d = wc + nj * 16 + l16;            // 0..63 within head
            const float bw = bias[n0 + d];
            const bool even = (d & 1) == 0;
            #pragma unroll
            for (int mi = 0; mi < 4; ++mi) {
                #pragma unroll
                for (int r = 0; r < 4; ++r) {
                    const int m = m0 + wr + mi * 16 + quad * 4 + r;
                    const int bb = m >> 11, s = m & (S_ - 1);
                    const float v = acc[mi][nj][r] + bw;
                    const float part = __shfl_xor(v, 1);         // pair value (d^1)
                    const float2 cs2 = rope[s * 32 + (d >> 1)];  // {cos, sin}
                    const float rot = even ? (v * cs2.x - part * cs2.y)
                                           : (v * cs2.x + part * cs2.y);
                    const ush pr = f2b(rot);
                    const ush pp = (ush)__shfl_xor((int)pr, 1);  // partner's rotated
                    if (even) {
                        const size_t o = (((size_t)bb * H_ + h) * S_ + s) * (size_t)D_ + d;
                        *(unsigned*)&Ob[o] = (unsigned)pr | ((unsigned)pp << 16);
                    }
                }
            }
        }
    } else {
        #pragma unroll
        for (int nj = 0; nj < 2; ++nj) {
            const int d = wc + nj * 16 + l16;
            const float bw = bias[n0 + d];
            #pragma unroll
            for (int mi = 0; mi < 4; ++mi) {
                const int m = m0 + wr + mi * 16 + quad * 4;  // r spans 4 consecutive s
                const int bb = m >> 11, sb = m & (S_ - 1);
                const size_t o = (((size_t)bb * H_ + h) * (size_t)D_ + d) * (size_t)S_ + sb;
                uint2 pk;
                pk.x = pack2(acc[mi][nj][0] + bw, acc[mi][nj][1] + bw);
                pk.y = pack2(acc[mi][nj][2] + bw, acc[mi][nj][3] + bw);
                *(uint2*)&Vtb[o] = pk;
            }
        }
    }
}

// ---------------------------------------------------------------------------
// Kernel 2: MFMA flash attention, FIXED-MAX softmax (m=0) — unchanged except
// the output is stored bf16 (fc consumed Att as bf16 anyway; this just moves
// the conversion and halves Att traffic). grid (S/64, H, B), block 256.
// ---------------------------------------------------------------------------
__global__ __launch_bounds__(256) void attn_kernel(
    const ush* __restrict__ Qb, const ush* __restrict__ Kb, const ush* __restrict__ Vtb,
    const float* __restrict__ pb, const int* __restrict__ mask, const float* __restrict__ coeff,
    ush* __restrict__ Att)
{
    __shared__ ush  Ks[64 * 72];       // [key][d]
    __shared__ ush  Vt[80 * 72];       // [d][key]; rows 64..79 = ones-column block
    __shared__ ush  Ps[64 * 72];       // P rows [q][key]
    __shared__ float kb_s[64];         // per-key bias: (mask?0:-1e30) - ch*pb[k]

    const int q0 = blockIdx.x * 64;
    const int h  = blockIdx.y;
    const int b  = blockIdx.z;
    const int t  = threadIdx.x;
    const int wid = t >> 6;
    const int lane = t & 63;
    const int quad = lane >> 4;
    const int l16  = lane & 15;

    const int bh = b * H_ + h;
    const float ch = coeff[h];

    // ones-column rows (written once; staging only touches rows 0..63)
    {
        int r2 = 64 + (t >> 4);        // 64..79
        int k2 = (t & 15) * 4;         // 0..60
        ush v = (r2 == 64) ? (ush)0x3F80 : (ush)0;   // bf16 1.0 / 0.0
        Vt[r2 * 72 + k2 + 0] = v;
        Vt[r2 * 72 + k2 + 1] = v;
        Vt[r2 * 72 + k2 + 2] = v;
        Vt[r2 * 72 + k2 + 3] = v;
    }

    const int qrow = q0 + wid * 16 + l16;
    short8 aQ[2];
    #pragma unroll
    for (int ks = 0; ks < 2; ++ks)
        aQ[ks] = *(const short8*)&Qb[((size_t)bh * S_ + qrow) * D_ + quad * 8 + ks * 32];

    float hp[4];
    #pragma unroll
    for (int r = 0; r < 4; ++r)
        hp[r] = ch * pb[b * S_ + q0 + wid * 16 + quad * 4 + r];

    f32x4 O[5];                        // O[4] = row-sum accumulator (ones-column)
    #pragma unroll
    for (int g = 0; g < 5; ++g) O[g] = (f32x4){0.f, 0.f, 0.f, 0.f};

    for (int kt = 0; kt < S_ / 64; ++kt) {
        const int k0 = kt * 64;
        __syncthreads();               // prior tile's frag reads done (also orders init)
        {
            const uint4* srcK = (const uint4*)(Kb + ((size_t)bh * S_ + k0) * D_);
            #pragma unroll
            for (int it = 0; it < 2; ++it) {
                int idx = t + it * 256;
                int row = idx >> 3, chk = idx & 7;
                *(uint4*)&Ks[row * 72 + chk * 8] = srcK[idx];
                const uint4* srcV = (const uint4*)(Vtb + ((size_t)bh * D_ + row) * S_ + k0);
                *(uint4*)&Vt[row * 72 + chk * 8] = srcV[chk];
            }
        }
        if (t < 64) {
            int gi = b * S_ + k0 + t;
            kb_s[t] = (mask[gi] ? 0.f : -1e30f) - ch * pb[gi];
        }
        __syncthreads();

        // ---- QK^T ----
        f32x4 Sc[4];
        #pragma unroll
        for (int cg = 0; cg < 4; ++cg) Sc[cg] = (f32x4){0.f, 0.f, 0.f, 0.f};
        #pragma unroll
        for (int ks = 0; ks < 2; ++ks) {
            #pragma unroll
            for (int cg = 0; cg < 4; ++cg) {
                short8 bK = *(const short8*)&Ks[(cg * 16 + l16) * 72 + quad * 8 + ks * 32];
                Sc[cg] = __builtin_amdgcn_mfma_f32_16x16x32_bf16(aQ[ks], bK, Sc[cg], 0, 0, 0);
            }
        }

        // ---- fixed-max softmax numerators -> Ps (bf16 truncation) ----
        float kbv[4];
        #pragma unroll
        for (int cg = 0; cg < 4; ++cg) kbv[cg] = kb_s[cg * 16 + l16];
        #pragma unroll
        for (int cg = 0; cg < 4; ++cg)
            #pragma unroll
            for (int r = 0; r < 4; ++r) {
                float s = fmaf(Sc[cg][r], 0.125f, hp[r] + kbv[cg]);
                float p = __expf(s);   // masked: s ~ -1e30 -> p = 0 exactly
                Ps[(wid * 16 + quad * 4 + r) * 72 + cg * 16 + l16] =
                    (ush)(__float_as_uint(p) >> 16);
            }
        __syncthreads();               // Ps visible to all lanes of this wave's rows

        // ---- PV (+ ones-column row-sum into O[4]) ----
        #pragma unroll
        for (int ks = 0; ks < 2; ++ks) {
            short8 aP = *(const short8*)&Ps[(wid * 16 + l16) * 72 + quad * 8 + ks * 32];
            #pragma unroll
            for (int g = 0; g < 5; ++g) {
                short8 bV = *(const short8*)&Vt[(g * 16 + l16) * 72 + quad * 8 + ks * 32];
                O[g] = __builtin_amdgcn_mfma_f32_16x16x32_bf16(aP, bV, O[g], 0, 0, 0);
            }
        }
    }

    // epilogue: l lives in lane l16==0 of each quad (col 64 of ones block)
    #pragma unroll
    for (int r = 0; r < 4; ++r) {
        const float l  = __shfl(O[4][r], (lane & 48));   // lane quad*16 (l16=0)
        const float rl = 1.f / l;
        const size_t ob = ((size_t)b * S_ + q0 + wid * 16 + quad * 4 + r) * E_ + h * 64;
        #pragma unroll
        for (int g = 0; g < 4; ++g)
            Att[ob + g * 16 + l16] = f2b(O[g][r] * rl);
    }
}

// ---------------------------------------------------------------------------
// Kernel 3: output projection, pure-bf16 MFMA GEMM, global_load_lds staging.
// Tile 64x64, BK=64, wave tile 32x32, acc[2][2]. grid (64,12)=768 (3/CU).
// Same chunk-swizzle scheme as kernel 1.
// ---------------------------------------------------------------------------
__global__ __launch_bounds__(256) void fc_mfma_kernel(
    const ush* __restrict__ Ain, const ush* __restrict__ W,
    const float* __restrict__ bias, float* __restrict__ Out)
{
    __shared__ ush As[64 * 64];
    __shared__ ush Bs[64 * 64];

    const int m0 = blockIdx.x * 64;
    const int n0 = blockIdx.y * 64;
    const int t  = threadIdx.x;
    const int wid  = t >> 6;
    const int lane = t & 63;
    const int quad = lane >> 4;
    const int l16  = lane & 15;
    const int wr = (wid >> 1) * 32;
    const int wc = (wid & 1) * 32;
    const int srow = lane >> 3;
    const int schk = lane & 7;

    f32x4 acc[2][2];
    #pragma unroll
    for (int i = 0; i < 2; ++i)
        #pragma unroll
        for (int j = 0; j < 2; ++j) acc[i][j] = (f32x4){0.f, 0.f, 0.f, 0.f};

    for (int kt = 0; kt < E_ / 64; ++kt) {
        const int kb = kt * 64;
        #pragma unroll
        for (int j = 0; j < 2; ++j) {
            const int r = wid * 16 + j * 8 + srow;
            const int c = schk ^ (r & 7);
            GLOAD16(&Ain[(size_t)(m0 + r) * E_ + kb + c * 8],
                    &As[(wid * 16 + j * 8) * 64]);
            GLOAD16(&W[(size_t)(n0 + r) * E_ + kb + c * 8],
                    &Bs[(wid * 16 + j * 8) * 64]);
        }
        __syncthreads();

        #pragma unroll
        for (int ks = 0; ks < 2; ++ks) {
            short8 bfr[2];
            #pragma unroll
            for (int nj = 0; nj < 2; ++nj) {
                const int rn = wc + nj * 16 + l16;
                bfr[nj] = *(const short8*)&Bs[rn * 64 + ((quad + ks * 4) ^ (rn & 7)) * 8];
            }
            #pragma unroll
            for (int mi = 0; mi < 2; ++mi) {
                const int rm = wr + mi * 16 + l16;
                short8 a = *(const short8*)&As[rm * 64 + ((quad + ks * 4) ^ (rm & 7)) * 8];
                acc[mi][0] = __builtin_amdgcn_mfma_f32_16x16x32_bf16(a, bfr[0], acc[mi][0], 0, 0, 0);
                acc[mi][1] = __builtin_amdgcn_mfma_f32_16x16x32_bf16(a, bfr[1], acc[mi][1], 0, 0, 0);
            }
        }
        __syncthreads();
    }

    #pragma unroll
    for (int nj = 0; nj < 2; ++nj) {
        const int n = n0 + wc + nj * 16 + l16;
        const float bw = bias[n];
        #pragma unroll
        for (int mi = 0; mi < 2; ++mi)
            #pragma unroll
            for (int r = 0; r < 4; ++r) {
                const int m = m0 + wr + mi * 16 + quad * 4 + r;
                Out[(size_t)m * E_ + n] = acc[mi][nj][r] + bw;
            }
    }
}

// ---------------------------------------------------------------------------
extern "C" void kernel_launch(void* const* d_in, const int* in_sizes, int n_in,
                              void* d_out, int out_size, void* d_ws, size_t ws_size,
                              hipStream_t stream)
{
    const float* q_in  = (const float*)d_in[0];
    const float* k_in  = (const float*)d_in[1];
    const float* v_in  = (const float*)d_in[2];
    const float* pb    = (const float*)d_in[3];
    const int*   mask  = (const int*)d_in[4];
    const float* wq    = (const float*)d_in[5];
    const float* bq    = (const float*)d_in[6];
    const float* wk    = (const float*)d_in[7];
    const float* bk    = (const float*)d_in[8];
    const float* wv    = (const float*)d_in[9];
    const float* bv    = (const float*)d_in[10];
    const float* fw    = (const float*)d_in[11];
    const float* fb    = (const float*)d_in[12];
    const float* coeff = (const float*)d_in[13];
    float* out = (float*)d_out;

    const size_t per = (size_t)B_ * H_ * S_ * D_;   // 3,145,728 elements
    const size_t wel = (size_t)E_ * E_;             //   589,824 elements

    // Workspace layout (~43 MB). Xqb is dead after qkv -> Att aliases it.
    ush* Qb   = (ush*)d_ws;
    ush* Kb   = Qb  + per;
    ush* Vtb  = Kb  + per;
    ush* Xqb  = Vtb + per;
    ush* Xkb  = Xqb + per;
    ush* Xvb  = Xkb + per;
    ush* Wqb  = Xvb + per;
    ush* Wkb  = Wqb + wel;
    ush* Wvb  = Wkb + wel;
    ush* Wfb  = Wvb + wel;
    float2* rope = (float2*)(Wfb + wel);            // [S][32], 512 KB (8B-aligned)
    ush* Attb = Xqb;                                // alias, live after qkv

    convert_kernel<<<dim3(6016), 256, 0, stream>>>(
        q_in, k_in, v_in, wq, wk, wv, fw,
        Xqb, Xkb, Xvb, Wqb, Wkb, Wvb, Wfb, rope);

    qkv_mfma_kernel<<<dim3(M_ / 128, H_, 3), 256, 0, stream>>>(
        Xqb, Xkb, Xvb, Wqb, Wkb, Wvb, bq, bk, bv, rope, Qb, Kb, Vtb);

    attn_kernel<<<dim3(S_ / 64, H_, B_), 256, 0, stream>>>(
        Qb, Kb, Vtb, pb, mask, coeff, Attb);

    fc_mfma_kernel<<<dim3(M_ / 64, E_ / 64), 256, 0, stream>>>(Attb, Wfb, fb, out);
}